// Round 7
// baseline (258.129 us; speedup 1.0000x reference)
//
#include <hip/hip_runtime.h>

#define Tt 2048
#define Cc 512
#define Bb 4
#define BC (Bb * Cc)

typedef __attribute__((ext_vector_type(4))) float f32x4;
typedef __attribute__((ext_vector_type(8))) _Float16 f16x8;
typedef __attribute__((ext_vector_type(4))) _Float16 f16x4;

// ---------------------------------------------------------------------------
// Kernel 0: W[k][n] (x4) -> Wt[z][n][k] fp16.
// ---------------------------------------------------------------------------
__global__ __launch_bounds__(256) void wsetup(
    const float* __restrict__ Wq, const float* __restrict__ Wk,
    const float* __restrict__ Wv, const float* __restrict__ Wo,
    _Float16* __restrict__ Wt)
{
    const int z = blockIdx.y;
    const float* W = (z == 0) ? Wq : (z == 1) ? Wk : (z == 2) ? Wv : Wo;
    const int k0 = (blockIdx.x >> 3) * 64, n0 = (blockIdx.x & 7) * 64;
    const int tid = threadIdx.x;
    __shared__ float tile[64][65];

#pragma unroll
    for (int i = 0; i < 4; ++i) {
        const int idx = i * 256 + tid;
        const int kr = idx >> 4, c4 = idx & 15;
        float4 v = *(const float4*)&W[(size_t)(k0 + kr) * Cc + n0 + c4 * 4];
        tile[kr][c4 * 4 + 0] = v.x; tile[kr][c4 * 4 + 1] = v.y;
        tile[kr][c4 * 4 + 2] = v.z; tile[kr][c4 * 4 + 3] = v.w;
    }
    __syncthreads();
#pragma unroll
    for (int i = 0; i < 4; ++i) {
        const int idx = i * 256 + tid;
        const int nr = idx >> 4, k4 = idx & 15;
        f16x4 o;
        o[0] = (_Float16)tile[k4 * 4 + 0][nr];
        o[1] = (_Float16)tile[k4 * 4 + 1][nr];
        o[2] = (_Float16)tile[k4 * 4 + 2][nr];
        o[3] = (_Float16)tile[k4 * 4 + 3][nr];
        *(f16x4*)&Wt[((size_t)(z * 512 + n0 + nr)) * Cc + k0 + k4 * 4] = o;
    }
}

// ---------------------------------------------------------------------------
// Kernel 1: QKV GEMM, fp16 MFMA. z==2 writes V TRANSPOSED (VT[b][c][t]) so
// the separate transpose kernel disappears. Column sum-of-squares goes to
// colpart[z][b][i][c] (block-exclusive stores -> no atomics, no memset).
// ---------------------------------------------------------------------------
__global__ __launch_bounds__(256, 3) void qkv_mfma(
    const float* __restrict__ HS, const _Float16* __restrict__ Wt,
    _Float16* __restrict__ Qf, _Float16* __restrict__ Kf,
    _Float16* __restrict__ VT, float* __restrict__ colpart)
{
    const int mt = blockIdx.x;              // 64
    const int nt = blockIdx.y;              // 4
    const int z  = blockIdx.z;              // 3

    const int tid = threadIdx.x;
    const int wave = tid >> 6, lane = tid & 63;
    const int quad = lane >> 4, lm = lane & 15;
    const int wm = (wave & 1) * 64, wn = (wave >> 1) * 64;

    __shared__ _Float16 sA[128 * 40];
    __shared__ _Float16 sB[128 * 40];
    __shared__ float sCS[4][64];

    f32x4 acc[4][4];
#pragma unroll
    for (int mf = 0; mf < 4; ++mf)
#pragma unroll
        for (int nf = 0; nf < 4; ++nf) acc[mf][nf] = (f32x4){0.f, 0.f, 0.f, 0.f};

    const int r2 = tid >> 1, kc = (tid & 1) * 16;
    const float* ga = HS + (size_t)(mt * 128 + r2) * Cc + kc;
    const _Float16* gb = Wt + ((size_t)(z * 512 + nt * 128 + r2)) * Cc + kc;

    for (int k0 = 0; k0 < Cc; k0 += 32) {
        __syncthreads();
        {
            float4 a0 = *(const float4*)&ga[k0];
            float4 a1 = *(const float4*)&ga[k0 + 4];
            float4 a2 = *(const float4*)&ga[k0 + 8];
            float4 a3 = *(const float4*)&ga[k0 + 12];
            f16x8 h0, h1;
            h0[0] = (_Float16)a0.x; h0[1] = (_Float16)a0.y;
            h0[2] = (_Float16)a0.z; h0[3] = (_Float16)a0.w;
            h0[4] = (_Float16)a1.x; h0[5] = (_Float16)a1.y;
            h0[6] = (_Float16)a1.z; h0[7] = (_Float16)a1.w;
            h1[0] = (_Float16)a2.x; h1[1] = (_Float16)a2.y;
            h1[2] = (_Float16)a2.z; h1[3] = (_Float16)a2.w;
            h1[4] = (_Float16)a3.x; h1[5] = (_Float16)a3.y;
            h1[6] = (_Float16)a3.z; h1[7] = (_Float16)a3.w;
            *(f16x8*)&sA[r2 * 40 + kc]     = h0;
            *(f16x8*)&sA[r2 * 40 + kc + 8] = h1;
            *(f16x8*)&sB[r2 * 40 + kc]     = *(const f16x8*)&gb[k0];
            *(f16x8*)&sB[r2 * 40 + kc + 8] = *(const f16x8*)&gb[k0 + 8];
        }
        __syncthreads();

        f16x8 ah[4], bh[4];
#pragma unroll
        for (int mf = 0; mf < 4; ++mf)
            ah[mf] = *(const f16x8*)&sA[(wm + mf * 16 + lm) * 40 + quad * 8];
#pragma unroll
        for (int nf = 0; nf < 4; ++nf)
            bh[nf] = *(const f16x8*)&sB[(wn + nf * 16 + lm) * 40 + quad * 8];
#pragma unroll
        for (int mf = 0; mf < 4; ++mf)
#pragma unroll
            for (int nf = 0; nf < 4; ++nf)
                acc[mf][nf] = __builtin_amdgcn_mfma_f32_16x16x32_f16(ah[mf], bh[nf], acc[mf][nf], 0, 0, 0);
    }

    const int bidx = mt >> 4, ii = mt & 15;
#pragma unroll
    for (int nf = 0; nf < 4; ++nf) {
        float cs = 0.f;
        const int c = nt * 128 + wn + nf * 16 + lm;
#pragma unroll
        for (int mf = 0; mf < 4; ++mf) {
            f16x4 pk;
#pragma unroll
            for (int r = 0; r < 4; ++r) {
                const float v = acc[mf][nf][r];
                cs += v * v;
                pk[r] = (_Float16)v;
            }
            if (z == 2) {
                const int tb = ii * 128 + wm + mf * 16 + quad * 4;
                *(f16x4*)&VT[((size_t)bidx * Cc + c) * Tt + tb] = pk;
            } else {
                _Float16* Out = (z == 0) ? Qf : Kf;
                const size_t m = (size_t)(mt * 128 + wm + mf * 16 + quad * 4);
                Out[(m + 0) * Cc + c] = pk[0];
                Out[(m + 1) * Cc + c] = pk[1];
                Out[(m + 2) * Cc + c] = pk[2];
                Out[(m + 3) * Cc + c] = pk[3];
            }
        }
        cs += __shfl_xor(cs, 16, 64);
        cs += __shfl_xor(cs, 32, 64);
        if (lane < 16) sCS[wave][nf * 16 + lane] = cs;
    }
    __syncthreads();
    if (tid < 128) {
        const int c = tid;
        const int wp = c >> 6;          // 0: waves 0,1 (wn=0); 1: waves 2,3
        const float s = sCS[wp * 2][c & 63] + sCS[wp * 2 + 1][c & 63];
        colpart[(((size_t)z * 4 + bidx) * 16 + ii) * Cc + nt * 128 + c] = s;
    }
}

// ---------------------------------------------------------------------------
// Kernel 2: barrier-free fp16 MFMA flash attention (S^T / O^T form).
//  - K and VT fragments read DIRECTLY from global (L2) into registers; LDS
//    holds only the wave-private P round-trip -> NO __syncthreads in K-loop.
//  - bh in low 5 bits of blockIdx => XCD = h (round-robin) pins each head's
//    K/VT/Q slices (~3 MB) in one XCD's 4 MB L2.
//  - inv computed inline from colpart (1/sqrt(mean+eps)).
//  - softmax via exp2 with log2(e) folded into Q scale.
// ---------------------------------------------------------------------------
#define LSTR 72

__global__ __launch_bounds__(256, 2) void attn_mfma(
    const _Float16* __restrict__ Qf, const _Float16* __restrict__ Kf,
    const _Float16* __restrict__ VT, const float* __restrict__ colpart,
    _Float16* __restrict__ AO)
{
    const int blk = blockIdx.x;           // 512: bh = low 5 bits (XCD pin)
    const int bh = blk & 31, qt = blk >> 5;
    const int b = bh >> 3, h = bh & 7;
    const int tid = threadIdx.x;
    const int wave = tid >> 6, lane = tid & 63;
    const int quad = lane >> 4, lm = lane & 15;

    __shared__ _Float16 sP[4 * 32 * LSTR];
    __shared__ float sInv[192];           // [0,64): iq  [64,128): ik  [128,192): iv
    _Float16* myP = sP + wave * 32 * LSTR;

    if (tid < 192) {
        const int z = tid >> 6, cr = tid & 63;
        const float* cp = colpart + (((size_t)z * 4 + b) * 16) * Cc + h * 64 + cr;
        float s = 0.f;
#pragma unroll
        for (int i = 0; i < 16; ++i) s += cp[(size_t)i * Cc];
        sInv[tid] = rsqrtf(s * (1.0f / Tt) + 1e-4f);
    }
    __syncthreads();

    // Q fragments (B-operand: n=lm=query, k=quad*8+j); iq*ik*scale*log2e folded
    const float QSC = 0.125f * 1.44269504088896f;
    f16x8 qb[2][2];
#pragma unroll
    for (int qf = 0; qf < 2; ++qf) {
        const int row = qt * 128 + wave * 32 + qf * 16 + lm;
#pragma unroll
        for (int ks = 0; ks < 2; ++ks) {
            const int d0 = ks * 32 + quad * 8;
            f16x8 qv = *(const f16x8*)&Qf[(size_t)(b * Tt + row) * Cc + h * 64 + d0];
#pragma unroll
            for (int j = 0; j < 8; ++j)
                qb[qf][ks][j] =
                    (_Float16)((float)qv[j] * sInv[d0 + j] * sInv[64 + d0 + j] * QSC);
        }
    }

    f32x4 o[4][2];      // [cf][qf]: O^T frags (m=channel, n=query)
#pragma unroll
    for (int cf = 0; cf < 4; ++cf)
#pragma unroll
        for (int qf = 0; qf < 2; ++qf) o[cf][qf] = (f32x4){0.f, 0.f, 0.f, 0.f};
    float ls[2] = {0.f, 0.f};

    const _Float16* gK = Kf + (size_t)b * Tt * Cc + h * 64;
    const _Float16* gV = VT + ((size_t)b * Cc + h * 64) * Tt;

    for (int kt = 0; kt < 32; ++kt) {
        const int t0 = kt * 64;

        // ---- operand fragments straight from global (L2)
        f16x8 ka[4][2], va[4][2];
#pragma unroll
        for (int kf = 0; kf < 4; ++kf)
#pragma unroll
            for (int ks = 0; ks < 2; ++ks)
                ka[kf][ks] = *(const f16x8*)
                    &gK[(size_t)(t0 + kf * 16 + lm) * Cc + ks * 32 + quad * 8];
#pragma unroll
        for (int cf = 0; cf < 4; ++cf)
#pragma unroll
            for (int ks = 0; ks < 2; ++ks)
                va[cf][ks] = *(const f16x8*)
                    &gV[(size_t)(cf * 16 + lm) * Tt + t0 + ks * 32 + quad * 8];

        // ---- S^T = K Q^T
        f32x4 st[4][2];
#pragma unroll
        for (int kf = 0; kf < 4; ++kf)
#pragma unroll
            for (int qf = 0; qf < 2; ++qf) st[kf][qf] = (f32x4){0.f, 0.f, 0.f, 0.f};
#pragma unroll
        for (int ks = 0; ks < 2; ++ks)
#pragma unroll
            for (int kf = 0; kf < 4; ++kf)
#pragma unroll
                for (int qf = 0; qf < 2; ++qf)
                    st[kf][qf] = __builtin_amdgcn_mfma_f32_16x16x32_f16(
                        ka[kf][ks], qb[qf][ks], st[kf][qf], 0, 0, 0);

        // ---- p = exp2(s') = exp(s); P rows packed b64; l partials
#pragma unroll
        for (int kf = 0; kf < 4; ++kf)
#pragma unroll
            for (int qf = 0; qf < 2; ++qf) {
                f16x4 pk;
#pragma unroll
                for (int r = 0; r < 4; ++r) {
                    const float p = exp2f(st[kf][qf][r]);
                    ls[qf] += p;
                    pk[r] = (_Float16)p;
                }
                *(f16x4*)&myP[(qf * 16 + lm) * LSTR + kf * 16 + quad * 4] = pk;
            }

        // ---- O^T += VT P^T   (P read back b128, wave-private: no barrier)
#pragma unroll
        for (int ks = 0; ks < 2; ++ks) {
            f16x8 pb[2];
#pragma unroll
            for (int qf = 0; qf < 2; ++qf)
                pb[qf] = *(const f16x8*)&myP[(qf * 16 + lm) * LSTR + ks * 32 + quad * 8];
#pragma unroll
            for (int cf = 0; cf < 4; ++cf)
#pragma unroll
                for (int qf = 0; qf < 2; ++qf)
                    o[cf][qf] = __builtin_amdgcn_mfma_f32_16x16x32_f16(
                        va[cf][ks], pb[qf], o[cf][qf], 0, 0, 0);
        }
    }

    // ---- epilogue: l reduce over quads, O /= l, * iv, fp16 out
    float il[2];
#pragma unroll
    for (int qf = 0; qf < 2; ++qf) {
        float s = ls[qf];
        s += __shfl_xor(s, 16, 64);
        s += __shfl_xor(s, 32, 64);
        il[qf] = 1.0f / s;
    }
#pragma unroll
    for (int qf = 0; qf < 2; ++qf) {
        const size_t row = (size_t)(b * Tt + qt * 128 + wave * 32 + qf * 16 + lm);
#pragma unroll
        for (int cf = 0; cf < 4; ++cf) {
            f16x4 pk;
#pragma unroll
            for (int r = 0; r < 4; ++r)
                pk[r] = (_Float16)(o[cf][qf][r] * il[qf] *
                                   sInv[128 + cf * 16 + quad * 4 + r]);
            *(f16x4*)&AO[row * Cc + h * 64 + cf * 16 + quad * 4] = pk;
        }
    }
}

// ---------------------------------------------------------------------------
// Kernel 3: out = AO @ Wo + bo + residual, fp16 MFMA. (unchanged)
// ---------------------------------------------------------------------------
__global__ __launch_bounds__(256, 2) void out_mfma(
    const _Float16* __restrict__ AO, const _Float16* __restrict__ Wt,
    const float* __restrict__ bo, const float* __restrict__ HS,
    float* __restrict__ Outp)
{
    const int mt = blockIdx.x;              // 128
    const int nt = blockIdx.y;              // 4
    const int tid = threadIdx.x;
    const int wave = tid >> 6, lane = tid & 63;
    const int quad = lane >> 4, lm = lane & 15;
    const int wm = (wave & 1) * 32, wn = (wave >> 1) * 64;

    __shared__ _Float16 sA[64 * 40];
    __shared__ _Float16 sB[128 * 40];

    f32x4 acc[2][4];
#pragma unroll
    for (int mf = 0; mf < 2; ++mf)
#pragma unroll
        for (int nf = 0; nf < 4; ++nf) acc[mf][nf] = (f32x4){0.f, 0.f, 0.f, 0.f};

    const int ra = tid >> 2, ka = (tid & 3) * 8;
    const int rb = tid >> 1, kb = (tid & 1) * 16;
    const _Float16* gah = AO + (size_t)(mt * 64 + ra) * Cc + ka;
    const _Float16* gbh = Wt + ((size_t)(3 * 512 + nt * 128 + rb)) * Cc + kb;

    for (int k0 = 0; k0 < Cc; k0 += 32) {
        __syncthreads();
        {
            *(f16x8*)&sA[ra * 40 + ka] = *(const f16x8*)&gah[k0];
            *(f16x8*)&sB[rb * 40 + kb]     = *(const f16x8*)&gbh[k0];
            *(f16x8*)&sB[rb * 40 + kb + 8] = *(const f16x8*)&gbh[k0 + 8];
        }
        __syncthreads();

        f16x8 ah[2], bh[4];
#pragma unroll
        for (int mf = 0; mf < 2; ++mf)
            ah[mf] = *(const f16x8*)&sA[(wm + mf * 16 + lm) * 40 + quad * 8];
#pragma unroll
        for (int nf = 0; nf < 4; ++nf)
            bh[nf] = *(const f16x8*)&sB[(wn + nf * 16 + lm) * 40 + quad * 8];
#pragma unroll
        for (int mf = 0; mf < 2; ++mf)
#pragma unroll
            for (int nf = 0; nf < 4; ++nf)
                acc[mf][nf] = __builtin_amdgcn_mfma_f32_16x16x32_f16(ah[mf], bh[nf], acc[mf][nf], 0, 0, 0);
    }

#pragma unroll
    for (int mf = 0; mf < 2; ++mf)
#pragma unroll
        for (int r = 0; r < 4; ++r) {
            const size_t m = (size_t)(mt * 64 + wm + mf * 16 + quad * 4 + r);
#pragma unroll
            for (int nf = 0; nf < 4; ++nf) {
                const int col = nt * 128 + wn + nf * 16 + lm;
                Outp[m * Cc + col] = acc[mf][nf][r] + bo[col] + HS[m * Cc + col];
            }
        }
}

// ---------------------------------------------------------------------------
extern "C" void kernel_launch(void* const* d_in, const int* in_sizes, int n_in,
                              void* d_out, int out_size, void* d_ws,
                              size_t ws_size, hipStream_t stream)
{
    const float* HS = (const float*)d_in[0];
    const float* Wq = (const float*)d_in[1];
    const float* Wk = (const float*)d_in[2];
    const float* Wv = (const float*)d_in[3];
    const float* Wo = (const float*)d_in[4];
    const float* bo = (const float*)d_in[5];
    float* out = (float*)d_out;

    const size_t SZ = (size_t)Bb * Tt * Cc;        // 4,194,304 elements
    _Float16* Qf  = (_Float16*)d_ws;
    _Float16* Kf  = Qf + SZ;
    _Float16* VTh = Kf + SZ;
    _Float16* AO  = VTh + SZ;
    _Float16* Wt  = AO + SZ;                        // 4*Cc*Cc halves
    float* colpart = (float*)(Wt + 4 * Cc * Cc);    // 3*4*16*512 floats

    wsetup<<<dim3(64, 4), 256, 0, stream>>>(Wq, Wk, Wv, Wo, Wt);

    qkv_mfma<<<dim3(64, 4, 3), 256, 0, stream>>>(HS, Wt, Qf, Kf, VTh, colpart);

    attn_mfma<<<512, 256, 0, stream>>>(Qf, Kf, VTh, colpart, AO);

    out_mfma<<<dim3(128, 4), 256, 0, stream>>>(AO, Wt, bo, HS, out);
}

// Round 8
// 222.803 us; speedup vs baseline: 1.1586x; 1.1586x over previous
//
#include <hip/hip_runtime.h>

#define Tt 2048
#define Cc 512
#define Bb 4
#define BC (Bb * Cc)

typedef __attribute__((ext_vector_type(4))) float f32x4;
typedef __attribute__((ext_vector_type(8))) _Float16 f16x8;
typedef __attribute__((ext_vector_type(4))) _Float16 f16x4;

// ---------------------------------------------------------------------------
// Kernel 0: W[k][n] (x4) -> Wt[z][n][k] fp16.
// ---------------------------------------------------------------------------
__global__ __launch_bounds__(256) void wsetup(
    const float* __restrict__ Wq, const float* __restrict__ Wk,
    const float* __restrict__ Wv, const float* __restrict__ Wo,
    _Float16* __restrict__ Wt)
{
    const int z = blockIdx.y;
    const float* W = (z == 0) ? Wq : (z == 1) ? Wk : (z == 2) ? Wv : Wo;
    const int k0 = (blockIdx.x >> 3) * 64, n0 = (blockIdx.x & 7) * 64;
    const int tid = threadIdx.x;
    __shared__ float tile[64][65];

#pragma unroll
    for (int i = 0; i < 4; ++i) {
        const int idx = i * 256 + tid;
        const int kr = idx >> 4, c4 = idx & 15;
        float4 v = *(const float4*)&W[(size_t)(k0 + kr) * Cc + n0 + c4 * 4];
        tile[kr][c4 * 4 + 0] = v.x; tile[kr][c4 * 4 + 1] = v.y;
        tile[kr][c4 * 4 + 2] = v.z; tile[kr][c4 * 4 + 3] = v.w;
    }
    __syncthreads();
#pragma unroll
    for (int i = 0; i < 4; ++i) {
        const int idx = i * 256 + tid;
        const int nr = idx >> 4, k4 = idx & 15;
        f16x4 o;
        o[0] = (_Float16)tile[k4 * 4 + 0][nr];
        o[1] = (_Float16)tile[k4 * 4 + 1][nr];
        o[2] = (_Float16)tile[k4 * 4 + 2][nr];
        o[3] = (_Float16)tile[k4 * 4 + 3][nr];
        *(f16x4*)&Wt[((size_t)(z * 512 + n0 + nr)) * Cc + k0 + k4 * 4] = o;
    }
}

// ---------------------------------------------------------------------------
// Kernel 1: QKV GEMM, fp16 MFMA.
//  z==0: Q row-major.
//  z==1: K in fragment-tiled layout Kt: 1KB chunks [t16][c32],
//        chunk id = ((b*128 + t>>4)*16 + c>>5), in-chunk = (t&15)*32 + (c&31).
//  z==2: V^T tiled VTt: chunks [c16][t32],
//        chunk id = ((b*32 + c>>4)*64 + t>>5), in-chunk = (c&15)*32 + (t&31).
//  colpart[z][b][ii][c] partial column sum-of-squares (block-exclusive).
// ---------------------------------------------------------------------------
__global__ __launch_bounds__(256, 3) void qkv_mfma(
    const float* __restrict__ HS, const _Float16* __restrict__ Wt,
    _Float16* __restrict__ Qf, _Float16* __restrict__ Kt,
    _Float16* __restrict__ VTt, float* __restrict__ colpart)
{
    const int mt = blockIdx.x;              // 64
    const int nt = blockIdx.y;              // 4
    const int z  = blockIdx.z;              // 3

    const int tid = threadIdx.x;
    const int wave = tid >> 6, lane = tid & 63;
    const int quad = lane >> 4, lm = lane & 15;
    const int wm = (wave & 1) * 64, wn = (wave >> 1) * 64;

    __shared__ _Float16 sA[128 * 40];
    __shared__ _Float16 sB[128 * 40];
    __shared__ float sCS[4][64];

    f32x4 acc[4][4];
#pragma unroll
    for (int mf = 0; mf < 4; ++mf)
#pragma unroll
        for (int nf = 0; nf < 4; ++nf) acc[mf][nf] = (f32x4){0.f, 0.f, 0.f, 0.f};

    const int r2 = tid >> 1, kc = (tid & 1) * 16;
    const float* ga = HS + (size_t)(mt * 128 + r2) * Cc + kc;
    const _Float16* gb = Wt + ((size_t)(z * 512 + nt * 128 + r2)) * Cc + kc;

    for (int k0 = 0; k0 < Cc; k0 += 32) {
        __syncthreads();
        {
            float4 a0 = *(const float4*)&ga[k0];
            float4 a1 = *(const float4*)&ga[k0 + 4];
            float4 a2 = *(const float4*)&ga[k0 + 8];
            float4 a3 = *(const float4*)&ga[k0 + 12];
            f16x8 h0, h1;
            h0[0] = (_Float16)a0.x; h0[1] = (_Float16)a0.y;
            h0[2] = (_Float16)a0.z; h0[3] = (_Float16)a0.w;
            h0[4] = (_Float16)a1.x; h0[5] = (_Float16)a1.y;
            h0[6] = (_Float16)a1.z; h0[7] = (_Float16)a1.w;
            h1[0] = (_Float16)a2.x; h1[1] = (_Float16)a2.y;
            h1[2] = (_Float16)a2.z; h1[3] = (_Float16)a2.w;
            h1[4] = (_Float16)a3.x; h1[5] = (_Float16)a3.y;
            h1[6] = (_Float16)a3.z; h1[7] = (_Float16)a3.w;
            *(f16x8*)&sA[r2 * 40 + kc]     = h0;
            *(f16x8*)&sA[r2 * 40 + kc + 8] = h1;
            *(f16x8*)&sB[r2 * 40 + kc]     = *(const f16x8*)&gb[k0];
            *(f16x8*)&sB[r2 * 40 + kc + 8] = *(const f16x8*)&gb[k0 + 8];
        }
        __syncthreads();

        f16x8 ah[4], bh[4];
#pragma unroll
        for (int mf = 0; mf < 4; ++mf)
            ah[mf] = *(const f16x8*)&sA[(wm + mf * 16 + lm) * 40 + quad * 8];
#pragma unroll
        for (int nf = 0; nf < 4; ++nf)
            bh[nf] = *(const f16x8*)&sB[(wn + nf * 16 + lm) * 40 + quad * 8];
#pragma unroll
        for (int mf = 0; mf < 4; ++mf)
#pragma unroll
            for (int nf = 0; nf < 4; ++nf)
                acc[mf][nf] = __builtin_amdgcn_mfma_f32_16x16x32_f16(ah[mf], bh[nf], acc[mf][nf], 0, 0, 0);
    }

    const int bidx = mt >> 4, ii = mt & 15;
#pragma unroll
    for (int nf = 0; nf < 4; ++nf) {
        float cs = 0.f;
        const int c = nt * 128 + wn + nf * 16 + lm;
#pragma unroll
        for (int mf = 0; mf < 4; ++mf) {
            f16x4 pk;
#pragma unroll
            for (int r = 0; r < 4; ++r) {
                const float v = acc[mf][nf][r];
                cs += v * v;
                pk[r] = (_Float16)v;
            }
            const int tg = mt * 128 + wm + mf * 16 + quad * 4;  // + r
            if (z == 0) {
#pragma unroll
                for (int r = 0; r < 4; ++r)
                    Qf[(size_t)(tg + r) * Cc + c] = pk[r];
            } else if (z == 1) {
                const int bb = tg >> 11, tl = (tg >> 4) & 127, csg = c >> 5;
                _Float16* base = Kt +
                    (((size_t)bb * 128 + tl) * 16 + csg) * 512 +
                    (tg & 15) * 32 + (c & 31);
#pragma unroll
                for (int r = 0; r < 4; ++r) base[r * 32] = pk[r];
            } else {
                const int bb = tg >> 11, ct = c >> 4, tt2 = (tg >> 5) & 63;
                *(f16x4*)&VTt[(((size_t)bb * 32 + ct) * 64 + tt2) * 512 +
                              (c & 15) * 32 + (tg & 31)] = pk;
            }
        }
        cs += __shfl_xor(cs, 16, 64);
        cs += __shfl_xor(cs, 32, 64);
        if (lane < 16) sCS[wave][nf * 16 + lane] = cs;
    }
    __syncthreads();
    if (tid < 128) {
        const int c = tid;
        const int wp = c >> 6;
        const float s = sCS[wp * 2][c & 63] + sCS[wp * 2 + 1][c & 63];
        colpart[(((size_t)z * 4 + bidx) * 16 + ii) * Cc + nt * 128 + c] = s;
    }
}

// ---------------------------------------------------------------------------
// Kernel 2: barrier-free fp16 MFMA flash attention (S^T / O^T form).
//  - K/VT operand fragments read DIRECT from L2 out of fragment-tiled
//    layouts: each wave load densely tiles one 1KB chunk (fixes R7).
//  - LDS only for the wave-private P round-trip; NO __syncthreads in K-loop.
//  - inv inline from colpart; softmax exp2 with log2e folded into Q scale.
// ---------------------------------------------------------------------------
#define LSTR 72

__global__ __launch_bounds__(256, 2) void attn_mfma(
    const _Float16* __restrict__ Qf, const _Float16* __restrict__ Kt,
    const _Float16* __restrict__ VTt, const float* __restrict__ colpart,
    _Float16* __restrict__ AO)
{
    const int blk = blockIdx.x;           // 512: bh in low 5 bits (XCD pin)
    const int bh = blk & 31, qt = blk >> 5;
    const int b = bh >> 3, h = bh & 7;
    const int tid = threadIdx.x;
    const int wave = tid >> 6, lane = tid & 63;
    const int quad = lane >> 4, lm = lane & 15;

    __shared__ _Float16 sP[4 * 32 * LSTR];
    __shared__ float sInv[192];           // iq | ik | iv
    _Float16* myP = sP + wave * 32 * LSTR;

    if (tid < 192) {
        const int z = tid >> 6, cr = tid & 63;
        const float* cp = colpart + (((size_t)z * 4 + b) * 16) * Cc + h * 64 + cr;
        float s = 0.f;
#pragma unroll
        for (int i = 0; i < 16; ++i) s += cp[(size_t)i * Cc];
        sInv[tid] = rsqrtf(s * (1.0f / Tt) + 1e-4f);
    }
    __syncthreads();

    // Q fragments (B-operand: n=lm=query, k=quad*8+j); iq*ik*scale*log2e folded
    const float QSC = 0.125f * 1.44269504088896f;
    f16x8 qb[2][2];
#pragma unroll
    for (int qf = 0; qf < 2; ++qf) {
        const int row = qt * 128 + wave * 32 + qf * 16 + lm;
#pragma unroll
        for (int ks = 0; ks < 2; ++ks) {
            const int d0 = ks * 32 + quad * 8;
            f16x8 qv = *(const f16x8*)&Qf[(size_t)(b * Tt + row) * Cc + h * 64 + d0];
#pragma unroll
            for (int j = 0; j < 8; ++j)
                qb[qf][ks][j] =
                    (_Float16)((float)qv[j] * sInv[d0 + j] * sInv[64 + d0 + j] * QSC);
        }
    }

    f32x4 o[4][2];      // [cf][qf]: O^T frags (m=channel, n=query)
#pragma unroll
    for (int cf = 0; cf < 4; ++cf)
#pragma unroll
        for (int qf = 0; qf < 2; ++qf) o[cf][qf] = (f32x4){0.f, 0.f, 0.f, 0.f};
    float ls[2] = {0.f, 0.f};

    const int lofs = lm * 32 + quad * 8;      // dense in-chunk offset
    const _Float16* kbase = Kt + (((size_t)b * 128) * 16 + h * 2) * 512 + lofs;
    const _Float16* vbase = VTt + (((size_t)b * 32 + h * 4) * 64) * 512 + lofs;

    for (int kt = 0; kt < 32; ++kt) {
        // ---- operand fragments: dense 1KB chunk loads from L2
        f16x8 ka[4][2], va[4][2];
#pragma unroll
        for (int kf = 0; kf < 4; ++kf)
#pragma unroll
            for (int ks = 0; ks < 2; ++ks)
                ka[kf][ks] = *(const f16x8*)
                    &kbase[((size_t)(kt * 4 + kf) * 16 + ks) * 512];
#pragma unroll
        for (int cf = 0; cf < 4; ++cf)
#pragma unroll
            for (int ks = 0; ks < 2; ++ks)
                va[cf][ks] = *(const f16x8*)
                    &vbase[((size_t)cf * 64 + kt * 2 + ks) * 512];

        // ---- S^T = K Q^T
        f32x4 st[4][2];
#pragma unroll
        for (int kf = 0; kf < 4; ++kf)
#pragma unroll
            for (int qf = 0; qf < 2; ++qf) st[kf][qf] = (f32x4){0.f, 0.f, 0.f, 0.f};
#pragma unroll
        for (int ks = 0; ks < 2; ++ks)
#pragma unroll
            for (int kf = 0; kf < 4; ++kf)
#pragma unroll
                for (int qf = 0; qf < 2; ++qf)
                    st[kf][qf] = __builtin_amdgcn_mfma_f32_16x16x32_f16(
                        ka[kf][ks], qb[qf][ks], st[kf][qf], 0, 0, 0);

        // ---- p = exp2(s'); P rows (query-major) packed b64; l partials
#pragma unroll
        for (int kf = 0; kf < 4; ++kf)
#pragma unroll
            for (int qf = 0; qf < 2; ++qf) {
                f16x4 pk;
#pragma unroll
                for (int r = 0; r < 4; ++r) {
                    const float p = exp2f(st[kf][qf][r]);
                    ls[qf] += p;
                    pk[r] = (_Float16)p;
                }
                *(f16x4*)&myP[(qf * 16 + lm) * LSTR + kf * 16 + quad * 4] = pk;
            }

        // ---- O^T += VT P^T (P read back b128; wave-private, no barrier)
#pragma unroll
        for (int ks = 0; ks < 2; ++ks) {
            f16x8 pb[2];
#pragma unroll
            for (int qf = 0; qf < 2; ++qf)
                pb[qf] = *(const f16x8*)&myP[(qf * 16 + lm) * LSTR + ks * 32 + quad * 8];
#pragma unroll
            for (int cf = 0; cf < 4; ++cf)
#pragma unroll
                for (int qf = 0; qf < 2; ++qf)
                    o[cf][qf] = __builtin_amdgcn_mfma_f32_16x16x32_f16(
                        va[cf][ks], pb[qf], o[cf][qf], 0, 0, 0);
        }
    }

    // ---- epilogue: l reduce over quads, O /= l, * iv, fp16 out
    float il[2];
#pragma unroll
    for (int qf = 0; qf < 2; ++qf) {
        float s = ls[qf];
        s += __shfl_xor(s, 16, 64);
        s += __shfl_xor(s, 32, 64);
        il[qf] = 1.0f / s;
    }
#pragma unroll
    for (int qf = 0; qf < 2; ++qf) {
        const size_t row = (size_t)(b * Tt + qt * 128 + wave * 32 + qf * 16 + lm);
#pragma unroll
        for (int cf = 0; cf < 4; ++cf) {
            f16x4 pk;
#pragma unroll
            for (int r = 0; r < 4; ++r)
                pk[r] = (_Float16)(o[cf][qf][r] * il[qf] *
                                   sInv[128 + cf * 16 + quad * 4 + r]);
            *(f16x4*)&AO[row * Cc + h * 64 + cf * 16 + quad * 4] = pk;
        }
    }
}

// ---------------------------------------------------------------------------
// Kernel 3: out = AO @ Wo + bo + residual, fp16 MFMA. (unchanged)
// ---------------------------------------------------------------------------
__global__ __launch_bounds__(256, 2) void out_mfma(
    const _Float16* __restrict__ AO, const _Float16* __restrict__ Wt,
    const float* __restrict__ bo, const float* __restrict__ HS,
    float* __restrict__ Outp)
{
    const int mt = blockIdx.x;              // 128
    const int nt = blockIdx.y;              // 4
    const int tid = threadIdx.x;
    const int wave = tid >> 6, lane = tid & 63;
    const int quad = lane >> 4, lm = lane & 15;
    const int wm = (wave & 1) * 32, wn = (wave >> 1) * 64;

    __shared__ _Float16 sA[64 * 40];
    __shared__ _Float16 sB[128 * 40];

    f32x4 acc[2][4];
#pragma unroll
    for (int mf = 0; mf < 2; ++mf)
#pragma unroll
        for (int nf = 0; nf < 4; ++nf) acc[mf][nf] = (f32x4){0.f, 0.f, 0.f, 0.f};

    const int ra = tid >> 2, ka = (tid & 3) * 8;
    const int rb = tid >> 1, kb = (tid & 1) * 16;
    const _Float16* gah = AO + (size_t)(mt * 64 + ra) * Cc + ka;
    const _Float16* gbh = Wt + ((size_t)(3 * 512 + nt * 128 + rb)) * Cc + kb;

    for (int k0 = 0; k0 < Cc; k0 += 32) {
        __syncthreads();
        {
            *(f16x8*)&sA[ra * 40 + ka] = *(const f16x8*)&gah[k0];
            *(f16x8*)&sB[rb * 40 + kb]     = *(const f16x8*)&gbh[k0];
            *(f16x8*)&sB[rb * 40 + kb + 8] = *(const f16x8*)&gbh[k0 + 8];
        }
        __syncthreads();

        f16x8 ah[2], bh[4];
#pragma unroll
        for (int mf = 0; mf < 2; ++mf)
            ah[mf] = *(const f16x8*)&sA[(wm + mf * 16 + lm) * 40 + quad * 8];
#pragma unroll
        for (int nf = 0; nf < 4; ++nf)
            bh[nf] = *(const f16x8*)&sB[(wn + nf * 16 + lm) * 40 + quad * 8];
#pragma unroll
        for (int mf = 0; mf < 2; ++mf)
#pragma unroll
            for (int nf = 0; nf < 4; ++nf)
                acc[mf][nf] = __builtin_amdgcn_mfma_f32_16x16x32_f16(ah[mf], bh[nf], acc[mf][nf], 0, 0, 0);
    }

#pragma unroll
    for (int mf = 0; mf < 2; ++mf)
#pragma unroll
        for (int r = 0; r < 4; ++r) {
            const size_t m = (size_t)(mt * 64 + wm + mf * 16 + quad * 4 + r);
#pragma unroll
            for (int nf = 0; nf < 4; ++nf) {
                const int col = nt * 128 + wn + nf * 16 + lm;
                Outp[m * Cc + col] = acc[mf][nf][r] + bo[col] + HS[m * Cc + col];
            }
        }
}

// ---------------------------------------------------------------------------
extern "C" void kernel_launch(void* const* d_in, const int* in_sizes, int n_in,
                              void* d_out, int out_size, void* d_ws,
                              size_t ws_size, hipStream_t stream)
{
    const float* HS = (const float*)d_in[0];
    const float* Wq = (const float*)d_in[1];
    const float* Wk = (const float*)d_in[2];
    const float* Wv = (const float*)d_in[3];
    const float* Wo = (const float*)d_in[4];
    const float* bo = (const float*)d_in[5];
    float* out = (float*)d_out;

    const size_t SZ = (size_t)Bb * Tt * Cc;        // 4,194,304 elements
    _Float16* Qf  = (_Float16*)d_ws;
    _Float16* Kt  = Qf + SZ;
    _Float16* VTt = Kt + SZ;
    _Float16* AO  = VTt + SZ;
    _Float16* Wt  = AO + SZ;                        // 4*Cc*Cc halves
    float* colpart = (float*)(Wt + 4 * Cc * Cc);    // 3*4*16*512 floats

    wsetup<<<dim3(64, 4), 256, 0, stream>>>(Wq, Wk, Wv, Wo, Wt);

    qkv_mfma<<<dim3(64, 4, 3), 256, 0, stream>>>(HS, Wt, Qf, Kt, VTt, colpart);

    attn_mfma<<<512, 256, 0, stream>>>(Qf, Kt, VTt, colpart, AO);

    out_mfma<<<dim3(128, 4), 256, 0, stream>>>(AO, Wt, bo, HS, out);
}

// Round 9
// 199.862 us; speedup vs baseline: 1.2915x; 1.1148x over previous
//
#include <hip/hip_runtime.h>

#define Tt 2048
#define Cc 512
#define Bb 4
#define BC (Bb * Cc)
#define BT (Bb * Tt)

typedef __attribute__((ext_vector_type(4))) float f32x4;
typedef __attribute__((ext_vector_type(8))) _Float16 f16x8;
typedef __attribute__((ext_vector_type(4))) _Float16 f16x4;

// ---------------------------------------------------------------------------
// Kernel 0: W[k][n] (x4) -> Wt[z][n][k] fp16.
// ---------------------------------------------------------------------------
__global__ __launch_bounds__(256) void wsetup(
    const float* __restrict__ Wq, const float* __restrict__ Wk,
    const float* __restrict__ Wv, const float* __restrict__ Wo,
    _Float16* __restrict__ Wt)
{
    const int z = blockIdx.y;
    const float* W = (z == 0) ? Wq : (z == 1) ? Wk : (z == 2) ? Wv : Wo;
    const int k0 = (blockIdx.x >> 3) * 64, n0 = (blockIdx.x & 7) * 64;
    const int tid = threadIdx.x;
    __shared__ float tile[64][65];

#pragma unroll
    for (int i = 0; i < 4; ++i) {
        const int idx = i * 256 + tid;
        const int kr = idx >> 4, c4 = idx & 15;
        float4 v = *(const float4*)&W[(size_t)(k0 + kr) * Cc + n0 + c4 * 4];
        tile[kr][c4 * 4 + 0] = v.x; tile[kr][c4 * 4 + 1] = v.y;
        tile[kr][c4 * 4 + 2] = v.z; tile[kr][c4 * 4 + 3] = v.w;
    }
    __syncthreads();
#pragma unroll
    for (int i = 0; i < 4; ++i) {
        const int idx = i * 256 + tid;
        const int nr = idx >> 4, k4 = idx & 15;
        f16x4 o;
        o[0] = (_Float16)tile[k4 * 4 + 0][nr];
        o[1] = (_Float16)tile[k4 * 4 + 1][nr];
        o[2] = (_Float16)tile[k4 * 4 + 2][nr];
        o[3] = (_Float16)tile[k4 * 4 + 3][nr];
        *(f16x4*)&Wt[((size_t)(z * 512 + n0 + nr)) * Cc + k0 + k4 * 4] = o;
    }
}

// ---------------------------------------------------------------------------
// Kernel 1: QKV GEMM, fp16 MFMA. z==2 writes V transposed (VT[b][c][t]);
// colpart[z][b][ii][c] block-exclusive column sum-of-squares partials.
// ---------------------------------------------------------------------------
__global__ __launch_bounds__(256, 3) void qkv_mfma(
    const float* __restrict__ HS, const _Float16* __restrict__ Wt,
    _Float16* __restrict__ Qf, _Float16* __restrict__ Kf,
    _Float16* __restrict__ VT, float* __restrict__ colpart)
{
    const int mt = blockIdx.x;              // 64
    const int nt = blockIdx.y;              // 4
    const int z  = blockIdx.z;              // 3

    const int tid = threadIdx.x;
    const int wave = tid >> 6, lane = tid & 63;
    const int quad = lane >> 4, lm = lane & 15;
    const int wm = (wave & 1) * 64, wn = (wave >> 1) * 64;

    __shared__ _Float16 sA[128 * 40];
    __shared__ _Float16 sB[128 * 40];
    __shared__ float sCS[4][64];

    f32x4 acc[4][4];
#pragma unroll
    for (int mf = 0; mf < 4; ++mf)
#pragma unroll
        for (int nf = 0; nf < 4; ++nf) acc[mf][nf] = (f32x4){0.f, 0.f, 0.f, 0.f};

    const int r2 = tid >> 1, kc = (tid & 1) * 16;
    const float* ga = HS + (size_t)(mt * 128 + r2) * Cc + kc;
    const _Float16* gb = Wt + ((size_t)(z * 512 + nt * 128 + r2)) * Cc + kc;

    for (int k0 = 0; k0 < Cc; k0 += 32) {
        __syncthreads();
        {
            float4 a0 = *(const float4*)&ga[k0];
            float4 a1 = *(const float4*)&ga[k0 + 4];
            float4 a2 = *(const float4*)&ga[k0 + 8];
            float4 a3 = *(const float4*)&ga[k0 + 12];
            f16x8 h0, h1;
            h0[0] = (_Float16)a0.x; h0[1] = (_Float16)a0.y;
            h0[2] = (_Float16)a0.z; h0[3] = (_Float16)a0.w;
            h0[4] = (_Float16)a1.x; h0[5] = (_Float16)a1.y;
            h0[6] = (_Float16)a1.z; h0[7] = (_Float16)a1.w;
            h1[0] = (_Float16)a2.x; h1[1] = (_Float16)a2.y;
            h1[2] = (_Float16)a2.z; h1[3] = (_Float16)a2.w;
            h1[4] = (_Float16)a3.x; h1[5] = (_Float16)a3.y;
            h1[6] = (_Float16)a3.z; h1[7] = (_Float16)a3.w;
            *(f16x8*)&sA[r2 * 40 + kc]     = h0;
            *(f16x8*)&sA[r2 * 40 + kc + 8] = h1;
            *(f16x8*)&sB[r2 * 40 + kc]     = *(const f16x8*)&gb[k0];
            *(f16x8*)&sB[r2 * 40 + kc + 8] = *(const f16x8*)&gb[k0 + 8];
        }
        __syncthreads();

        f16x8 ah[4], bh[4];
#pragma unroll
        for (int mf = 0; mf < 4; ++mf)
            ah[mf] = *(const f16x8*)&sA[(wm + mf * 16 + lm) * 40 + quad * 8];
#pragma unroll
        for (int nf = 0; nf < 4; ++nf)
            bh[nf] = *(const f16x8*)&sB[(wn + nf * 16 + lm) * 40 + quad * 8];
#pragma unroll
        for (int mf = 0; mf < 4; ++mf)
#pragma unroll
            for (int nf = 0; nf < 4; ++nf)
                acc[mf][nf] = __builtin_amdgcn_mfma_f32_16x16x32_f16(ah[mf], bh[nf], acc[mf][nf], 0, 0, 0);
    }

    const int bidx = mt >> 4, ii = mt & 15;
#pragma unroll
    for (int nf = 0; nf < 4; ++nf) {
        float cs = 0.f;
        const int c = nt * 128 + wn + nf * 16 + lm;
#pragma unroll
        for (int mf = 0; mf < 4; ++mf) {
            f16x4 pk;
#pragma unroll
            for (int r = 0; r < 4; ++r) {
                const float v = acc[mf][nf][r];
                cs += v * v;
                pk[r] = (_Float16)v;
            }
            if (z == 2) {
                const int tb = ii * 128 + wm + mf * 16 + quad * 4;
                *(f16x4*)&VT[((size_t)bidx * Cc + c) * Tt + tb] = pk;
            } else {
                _Float16* Out = (z == 0) ? Qf : Kf;
                const size_t m = (size_t)(mt * 128 + wm + mf * 16 + quad * 4);
                Out[(m + 0) * Cc + c] = pk[0];
                Out[(m + 1) * Cc + c] = pk[1];
                Out[(m + 2) * Cc + c] = pk[2];
                Out[(m + 3) * Cc + c] = pk[3];
            }
        }
        cs += __shfl_xor(cs, 16, 64);
        cs += __shfl_xor(cs, 32, 64);
        if (lane < 16) sCS[wave][nf * 16 + lane] = cs;
    }
    __syncthreads();
    if (tid < 128) {
        const int c = tid;
        const int wp = c >> 6;
        const float s = sCS[wp * 2][c & 63] + sCS[wp * 2 + 1][c & 63];
        colpart[(((size_t)z * 4 + bidx) * 16 + ii) * Cc + nt * 128 + c] = s;
    }
}

// ---------------------------------------------------------------------------
// Kernel 2: fp16 MFMA flash attention, S^T/O^T form, LDS-staged with
// register prefetch (R6 core), kt-CHUNKED x2 for occupancy (4 blocks/CU):
// each chunk covers 16 K-tiles, writes chunk-normalized O and its l;
// out_mfma blends. inv inline; exp2 softmax; iv folded into epilogue.
// ---------------------------------------------------------------------------
#define LSTR 72

__global__ __launch_bounds__(256, 4) void attn_mfma(
    const _Float16* __restrict__ Qf, const _Float16* __restrict__ Kf,
    const _Float16* __restrict__ VT, const float* __restrict__ colpart,
    _Float16* __restrict__ AO0, _Float16* __restrict__ AO1,
    float* __restrict__ Lc)
{
    const int blk = blockIdx.x;           // 1024: bh low 5 bits (XCD pin)
    const int bh = blk & 31;
    const int qt = (blk >> 5) & 15;
    const int chunk = blk >> 9;
    const int b = bh >> 3, h = bh & 7;
    const int tid = threadIdx.x;
    const int wave = tid >> 6, lane = tid & 63;
    const int quad = lane >> 4, lm = lane & 15;

    __shared__ _Float16 sK[64 * LSTR];
    __shared__ _Float16 sVT[64 * LSTR];
    __shared__ _Float16 sP[4 * 32 * LSTR];
    __shared__ float sInv[192];           // iq | ik | iv
    _Float16* myP = sP + wave * 32 * LSTR;

    if (tid < 192) {
        const int z = tid >> 6, cr = tid & 63;
        const float* cp = colpart + (((size_t)z * 4 + b) * 16) * Cc + h * 64 + cr;
        float s = 0.f;
#pragma unroll
        for (int i = 0; i < 16; ++i) s += cp[(size_t)i * Cc];
        sInv[tid] = rsqrtf(s * (1.0f / Tt) + 1e-4f);
    }
    __syncthreads();

    // Q fragments (B-operand: n=lm=query, k=quad*8+j); iq*ik*scale*log2e folded
    const float QSC = 0.125f * 1.44269504088896f;
    f16x8 qb[2][2];
#pragma unroll
    for (int qf = 0; qf < 2; ++qf) {
        const int row = qt * 128 + wave * 32 + qf * 16 + lm;
#pragma unroll
        for (int ks = 0; ks < 2; ++ks) {
            const int d0 = ks * 32 + quad * 8;
            f16x8 qv = *(const f16x8*)&Qf[(size_t)(b * Tt + row) * Cc + h * 64 + d0];
#pragma unroll
            for (int j = 0; j < 8; ++j)
                qb[qf][ks][j] =
                    (_Float16)((float)qv[j] * sInv[d0 + j] * sInv[64 + d0 + j] * QSC);
        }
    }

    f32x4 o[4][2];      // [cf][qf]: O^T frags (m=channel, n=query)
#pragma unroll
    for (int cf = 0; cf < 4; ++cf)
#pragma unroll
        for (int qf = 0; qf < 2; ++qf) o[cf][qf] = (f32x4){0.f, 0.f, 0.f, 0.f};
    float ls[2] = {0.f, 0.f};

    const int sr0 = tid >> 3, sc0 = (tid & 7) * 8;
    const int sr1 = sr0 + 32;
    const _Float16* gK = Kf + (size_t)b * Tt * Cc + h * 64;
    const _Float16* gV = VT + ((size_t)b * Cc + h * 64) * Tt;

    const int kt0 = chunk * 16;
    f16x8 rk0, rk1, rv0, rv1;
    {
        const int t0 = kt0 * 64;
        rk0 = *(const f16x8*)&gK[(size_t)(t0 + sr0) * Cc + sc0];
        rk1 = *(const f16x8*)&gK[(size_t)(t0 + sr1) * Cc + sc0];
        rv0 = *(const f16x8*)&gV[(size_t)sr0 * Tt + t0 + sc0];
        rv1 = *(const f16x8*)&gV[(size_t)sr1 * Tt + t0 + sc0];
    }

    for (int kt = kt0; kt < kt0 + 16; ++kt) {
        __syncthreads();
        *(f16x8*)&sK[sr0 * LSTR + sc0] = rk0;
        *(f16x8*)&sK[sr1 * LSTR + sc0] = rk1;
        *(f16x8*)&sVT[sr0 * LSTR + sc0] = rv0;
        *(f16x8*)&sVT[sr1 * LSTR + sc0] = rv1;
        __syncthreads();

        if (kt < kt0 + 15) {
            const int t0 = (kt + 1) * 64;
            rk0 = *(const f16x8*)&gK[(size_t)(t0 + sr0) * Cc + sc0];
            rk1 = *(const f16x8*)&gK[(size_t)(t0 + sr1) * Cc + sc0];
            rv0 = *(const f16x8*)&gV[(size_t)sr0 * Tt + t0 + sc0];
            rv1 = *(const f16x8*)&gV[(size_t)sr1 * Tt + t0 + sc0];
        }

        // ---- S^T = K Q^T
        f32x4 st[4][2];
#pragma unroll
        for (int kf = 0; kf < 4; ++kf)
#pragma unroll
            for (int qf = 0; qf < 2; ++qf) st[kf][qf] = (f32x4){0.f, 0.f, 0.f, 0.f};
#pragma unroll
        for (int ks = 0; ks < 2; ++ks) {
            f16x8 ka[4];
#pragma unroll
            for (int kf = 0; kf < 4; ++kf)
                ka[kf] = *(const f16x8*)&sK[(kf * 16 + lm) * LSTR + ks * 32 + quad * 8];
#pragma unroll
            for (int kf = 0; kf < 4; ++kf)
#pragma unroll
                for (int qf = 0; qf < 2; ++qf)
                    st[kf][qf] = __builtin_amdgcn_mfma_f32_16x16x32_f16(
                        ka[kf], qb[qf][ks], st[kf][qf], 0, 0, 0);
        }

        // ---- p = exp2(s'); P rows (query-major) packed b64; l partials
#pragma unroll
        for (int kf = 0; kf < 4; ++kf)
#pragma unroll
            for (int qf = 0; qf < 2; ++qf) {
                f16x4 pk;
#pragma unroll
                for (int r = 0; r < 4; ++r) {
                    const float p = exp2f(st[kf][qf][r]);
                    ls[qf] += p;
                    pk[r] = (_Float16)p;
                }
                *(f16x4*)&myP[(qf * 16 + lm) * LSTR + kf * 16 + quad * 4] = pk;
            }

        // ---- O^T += VT P^T (P wave-private)
#pragma unroll
        for (int ks = 0; ks < 2; ++ks) {
            f16x8 pb[2];
#pragma unroll
            for (int qf = 0; qf < 2; ++qf)
                pb[qf] = *(const f16x8*)&myP[(qf * 16 + lm) * LSTR + ks * 32 + quad * 8];
            f16x8 va[4];
#pragma unroll
            for (int cf = 0; cf < 4; ++cf)
                va[cf] = *(const f16x8*)&sVT[(cf * 16 + lm) * LSTR + ks * 32 + quad * 8];
#pragma unroll
            for (int cf = 0; cf < 4; ++cf)
#pragma unroll
                for (int qf = 0; qf < 2; ++qf)
                    o[cf][qf] = __builtin_amdgcn_mfma_f32_16x16x32_f16(
                        va[cf], pb[qf], o[cf][qf], 0, 0, 0);
        }
    }

    // ---- epilogue: chunk-l reduce over quads; O /= l_c; * iv; store + Lc
    _Float16* AOc = chunk ? AO1 : AO0;
    float il[2], lsum[2];
#pragma unroll
    for (int qf = 0; qf < 2; ++qf) {
        float s = ls[qf];
        s += __shfl_xor(s, 16, 64);
        s += __shfl_xor(s, 32, 64);
        lsum[qf] = s;
        il[qf] = 1.0f / s;
    }
#pragma unroll
    for (int qf = 0; qf < 2; ++qf) {
        const size_t row = (size_t)(b * Tt + qt * 128 + wave * 32 + qf * 16 + lm);
        if (quad == 0) Lc[(size_t)chunk * BT + row] = lsum[qf];
#pragma unroll
        for (int cf = 0; cf < 4; ++cf) {
            f16x4 pk;
#pragma unroll
            for (int r = 0; r < 4; ++r)
                pk[r] = (_Float16)(o[cf][qf][r] * il[qf] *
                                   sInv[128 + cf * 16 + quad * 4 + r]);
            *(f16x4*)&AOc[row * Cc + h * 64 + cf * 16 + quad * 4] = pk;
        }
    }
}

// ---------------------------------------------------------------------------
// Kernel 3: out = blend(AO0,AO1) @ Wo + bo + residual, fp16 MFMA.
// Blend weights w_c = l_c/(l0+l1) applied during A-staging.
// ---------------------------------------------------------------------------
__global__ __launch_bounds__(256, 2) void out_mfma(
    const _Float16* __restrict__ AO0, const _Float16* __restrict__ AO1,
    const float* __restrict__ Lc, const _Float16* __restrict__ Wt,
    const float* __restrict__ bo, const float* __restrict__ HS,
    float* __restrict__ Outp)
{
    const int mt = blockIdx.x;              // 128
    const int nt = blockIdx.y;              // 4
    const int tid = threadIdx.x;
    const int wave = tid >> 6, lane = tid & 63;
    const int quad = lane >> 4, lm = lane & 15;
    const int wm = (wave & 1) * 32, wn = (wave >> 1) * 64;

    __shared__ _Float16 sA[64 * 40];
    __shared__ _Float16 sB[128 * 40];

    f32x4 acc[2][4];
#pragma unroll
    for (int mf = 0; mf < 2; ++mf)
#pragma unroll
        for (int nf = 0; nf < 4; ++nf) acc[mf][nf] = (f32x4){0.f, 0.f, 0.f, 0.f};

    const int ra = tid >> 2, ka = (tid & 3) * 8;
    const int rb = tid >> 1, kb = (tid & 1) * 16;
    const size_t am = (size_t)(mt * 64 + ra);
    const _Float16* ga0 = AO0 + am * Cc + ka;
    const _Float16* ga1 = AO1 + am * Cc + ka;
    const _Float16* gbh = Wt + ((size_t)(3 * 512 + nt * 128 + rb)) * Cc + kb;

    const float l0 = Lc[am], l1 = Lc[BT + am];
    const float w0 = l0 / (l0 + l1), w1 = 1.0f - w0;

    for (int k0 = 0; k0 < Cc; k0 += 32) {
        __syncthreads();
        {
            f16x8 a0 = *(const f16x8*)&ga0[k0];
            f16x8 a1 = *(const f16x8*)&ga1[k0];
            f16x8 ab;
#pragma unroll
            for (int j = 0; j < 8; ++j)
                ab[j] = (_Float16)((float)a0[j] * w0 + (float)a1[j] * w1);
            *(f16x8*)&sA[ra * 40 + ka] = ab;
            *(f16x8*)&sB[rb * 40 + kb]     = *(const f16x8*)&gbh[k0];
            *(f16x8*)&sB[rb * 40 + kb + 8] = *(const f16x8*)&gbh[k0 + 8];
        }
        __syncthreads();

        f16x8 ah[2], bh[4];
#pragma unroll
        for (int mf = 0; mf < 2; ++mf)
            ah[mf] = *(const f16x8*)&sA[(wm + mf * 16 + lm) * 40 + quad * 8];
#pragma unroll
        for (int nf = 0; nf < 4; ++nf)
            bh[nf] = *(const f16x8*)&sB[(wn + nf * 16 + lm) * 40 + quad * 8];
#pragma unroll
        for (int mf = 0; mf < 2; ++mf)
#pragma unroll
            for (int nf = 0; nf < 4; ++nf)
                acc[mf][nf] = __builtin_amdgcn_mfma_f32_16x16x32_f16(ah[mf], bh[nf], acc[mf][nf], 0, 0, 0);
    }

#pragma unroll
    for (int mf = 0; mf < 2; ++mf)
#pragma unroll
        for (int r = 0; r < 4; ++r) {
            const size_t m = (size_t)(mt * 64 + wm + mf * 16 + quad * 4 + r);
#pragma unroll
            for (int nf = 0; nf < 4; ++nf) {
                const int col = nt * 128 + wn + nf * 16 + lm;
                Outp[m * Cc + col] = acc[mf][nf][r] + bo[col] + HS[m * Cc + col];
            }
        }
}

// ---------------------------------------------------------------------------
extern "C" void kernel_launch(void* const* d_in, const int* in_sizes, int n_in,
                              void* d_out, int out_size, void* d_ws,
                              size_t ws_size, hipStream_t stream)
{
    const float* HS = (const float*)d_in[0];
    const float* Wq = (const float*)d_in[1];
    const float* Wk = (const float*)d_in[2];
    const float* Wv = (const float*)d_in[3];
    const float* Wo = (const float*)d_in[4];
    const float* bo = (const float*)d_in[5];
    float* out = (float*)d_out;

    const size_t SZ = (size_t)Bb * Tt * Cc;        // 4,194,304 elements
    _Float16* Qf  = (_Float16*)d_ws;
    _Float16* Kf  = Qf + SZ;
    _Float16* VTh = Kf + SZ;
    _Float16* AO0 = VTh + SZ;
    _Float16* AO1 = AO0 + SZ;
    _Float16* Wt  = AO1 + SZ;                       // 4*Cc*Cc halves
    float* colpart = (float*)(Wt + 4 * Cc * Cc);    // 3*4*16*512 floats
    float* Lc      = colpart + 3 * 4 * 16 * Cc;     // 2*BT floats

    wsetup<<<dim3(64, 4), 256, 0, stream>>>(Wq, Wk, Wv, Wo, Wt);

    qkv_mfma<<<dim3(64, 4, 3), 256, 0, stream>>>(HS, Wt, Qf, Kf, VTh, colpart);

    attn_mfma<<<1024, 256, 0, stream>>>(Qf, Kf, VTh, colpart, AO0, AO1, Lc);

    out_mfma<<<dim3(128, 4), 256, 0, stream>>>(AO0, AO1, Lc, Wt, bo, HS, out);
}

// Round 11
// 185.058 us; speedup vs baseline: 1.3949x; 1.0800x over previous
//
#include <hip/hip_runtime.h>

#define Tt 2048
#define Cc 512
#define Bb 4
#define BC (Bb * Cc)

typedef __attribute__((ext_vector_type(4))) float f32x4;
typedef __attribute__((ext_vector_type(8))) _Float16 f16x8;
typedef __attribute__((ext_vector_type(4))) _Float16 f16x4;

// ---------------------------------------------------------------------------
// Kernel 0: W[k][n] (x4) -> Wt[z][n][k] fp16.
// ---------------------------------------------------------------------------
__global__ __launch_bounds__(256) void wsetup(
    const float* __restrict__ Wq, const float* __restrict__ Wk,
    const float* __restrict__ Wv, const float* __restrict__ Wo,
    _Float16* __restrict__ Wt)
{
    const int z = blockIdx.y;
    const float* W = (z == 0) ? Wq : (z == 1) ? Wk : (z == 2) ? Wv : Wo;
    const int k0 = (blockIdx.x >> 3) * 64, n0 = (blockIdx.x & 7) * 64;
    const int tid = threadIdx.x;
    __shared__ float tile[64][65];

#pragma unroll
    for (int i = 0; i < 4; ++i) {
        const int idx = i * 256 + tid;
        const int kr = idx >> 4, c4 = idx & 15;
        float4 v = *(const float4*)&W[(size_t)(k0 + kr) * Cc + n0 + c4 * 4];
        tile[kr][c4 * 4 + 0] = v.x; tile[kr][c4 * 4 + 1] = v.y;
        tile[kr][c4 * 4 + 2] = v.z; tile[kr][c4 * 4 + 3] = v.w;
    }
    __syncthreads();
#pragma unroll
    for (int i = 0; i < 4; ++i) {
        const int idx = i * 256 + tid;
        const int nr = idx >> 4, k4 = idx & 15;
        f16x4 o;
        o[0] = (_Float16)tile[k4 * 4 + 0][nr];
        o[1] = (_Float16)tile[k4 * 4 + 1][nr];
        o[2] = (_Float16)tile[k4 * 4 + 2][nr];
        o[3] = (_Float16)tile[k4 * 4 + 3][nr];
        *(f16x4*)&Wt[((size_t)(z * 512 + n0 + nr)) * Cc + k0 + k4 * 4] = o;
    }
}

// ---------------------------------------------------------------------------
// Kernel 1: QKV GEMM, fp16 MFMA (R9-validated). z==2 writes V transposed
// (VT[b][c][t]); colpart[z][b][ii][c] block-exclusive colsum partials.
// ---------------------------------------------------------------------------
__global__ __launch_bounds__(256, 3) void qkv_mfma(
    const float* __restrict__ HS, const _Float16* __restrict__ Wt,
    _Float16* __restrict__ Qf, _Float16* __restrict__ Kf,
    _Float16* __restrict__ VT, float* __restrict__ colpart)
{
    const int mt = blockIdx.x;              // 64
    const int nt = blockIdx.y;              // 4
    const int z  = blockIdx.z;              // 3

    const int tid = threadIdx.x;
    const int wave = tid >> 6, lane = tid & 63;
    const int quad = lane >> 4, lm = lane & 15;
    const int wm = (wave & 1) * 64, wn = (wave >> 1) * 64;

    __shared__ _Float16 sA[128 * 40];
    __shared__ _Float16 sB[128 * 40];
    __shared__ float sCS[4][64];

    f32x4 acc[4][4];
#pragma unroll
    for (int mf = 0; mf < 4; ++mf)
#pragma unroll
        for (int nf = 0; nf < 4; ++nf) acc[mf][nf] = (f32x4){0.f, 0.f, 0.f, 0.f};

    const int r2 = tid >> 1, kc = (tid & 1) * 16;
    const float* ga = HS + (size_t)(mt * 128 + r2) * Cc + kc;
    const _Float16* gb = Wt + ((size_t)(z * 512 + nt * 128 + r2)) * Cc + kc;

    for (int k0 = 0; k0 < Cc; k0 += 32) {
        __syncthreads();
        {
            float4 a0 = *(const float4*)&ga[k0];
            float4 a1 = *(const float4*)&ga[k0 + 4];
            float4 a2 = *(const float4*)&ga[k0 + 8];
            float4 a3 = *(const float4*)&ga[k0 + 12];
            f16x8 h0, h1;
            h0[0] = (_Float16)a0.x; h0[1] = (_Float16)a0.y;
            h0[2] = (_Float16)a0.z; h0[3] = (_Float16)a0.w;
            h0[4] = (_Float16)a1.x; h0[5] = (_Float16)a1.y;
            h0[6] = (_Float16)a1.z; h0[7] = (_Float16)a1.w;
            h1[0] = (_Float16)a2.x; h1[1] = (_Float16)a2.y;
            h1[2] = (_Float16)a2.z; h1[3] = (_Float16)a2.w;
            h1[4] = (_Float16)a3.x; h1[5] = (_Float16)a3.y;
            h1[6] = (_Float16)a3.z; h1[7] = (_Float16)a3.w;
            *(f16x8*)&sA[r2 * 40 + kc]     = h0;
            *(f16x8*)&sA[r2 * 40 + kc + 8] = h1;
            *(f16x8*)&sB[r2 * 40 + kc]     = *(const f16x8*)&gb[k0];
            *(f16x8*)&sB[r2 * 40 + kc + 8] = *(const f16x8*)&gb[k0 + 8];
        }
        __syncthreads();

        f16x8 ah[4], bh[4];
#pragma unroll
        for (int mf = 0; mf < 4; ++mf)
            ah[mf] = *(const f16x8*)&sA[(wm + mf * 16 + lm) * 40 + quad * 8];
#pragma unroll
        for (int nf = 0; nf < 4; ++nf)
            bh[nf] = *(const f16x8*)&sB[(wn + nf * 16 + lm) * 40 + quad * 8];
#pragma unroll
        for (int mf = 0; mf < 4; ++mf)
#pragma unroll
            for (int nf = 0; nf < 4; ++nf)
                acc[mf][nf] = __builtin_amdgcn_mfma_f32_16x16x32_f16(ah[mf], bh[nf], acc[mf][nf], 0, 0, 0);
    }

    const int bidx = mt >> 4, ii = mt & 15;
#pragma unroll
    for (int nf = 0; nf < 4; ++nf) {
        float cs = 0.f;
        const int c = nt * 128 + wn + nf * 16 + lm;
#pragma unroll
        for (int mf = 0; mf < 4; ++mf) {
            f16x4 pk;
#pragma unroll
            for (int r = 0; r < 4; ++r) {
                const float v = acc[mf][nf][r];
                cs += v * v;
                pk[r] = (_Float16)v;
            }
            if (z == 2) {
                const int tb = ii * 128 + wm + mf * 16 + quad * 4;
                *(f16x4*)&VT[((size_t)bidx * Cc + c) * Tt + tb] = pk;
            } else {
                _Float16* Out = (z == 0) ? Qf : Kf;
                const size_t m = (size_t)(mt * 128 + wm + mf * 16 + quad * 4);
                Out[(m + 0) * Cc + c] = pk[0];
                Out[(m + 1) * Cc + c] = pk[1];
                Out[(m + 2) * Cc + c] = pk[2];
                Out[(m + 3) * Cc + c] = pk[3];
            }
        }
        cs += __shfl_xor(cs, 16, 64);
        cs += __shfl_xor(cs, 32, 64);
        if (lane < 16) sCS[wave][nf * 16 + lane] = cs;
    }
    __syncthreads();
    if (tid < 128) {
        const int c = tid;
        const int wp = c >> 6;
        const float s = sCS[wp * 2][c & 63] + sCS[wp * 2 + 1][c & 63];
        colpart[(((size_t)z * 4 + bidx) * 16 + ii) * Cc + nt * 128 + c] = s;
    }
}

// ---------------------------------------------------------------------------
// Kernel 2: fp16 MFMA flash attention (R6 core, non-chunked), S^T/O^T form,
// LDS-staged K/VT with register prefetch; inline sInv from colpart;
// exp2 softmax; iv folded into epilogue. Grid 512 flat, bh in low 5 bits.
// ---------------------------------------------------------------------------
#define LSTR 72

__global__ __launch_bounds__(256, 2) void attn_mfma(
    const _Float16* __restrict__ Qf, const _Float16* __restrict__ Kf,
    const _Float16* __restrict__ VT, const float* __restrict__ colpart,
    _Float16* __restrict__ AO)
{
    const int blk = blockIdx.x;           // 512: bh low 5 bits (XCD pin)
    const int bh = blk & 31, qt = blk >> 5;
    const int b = bh >> 3, h = bh & 7;
    const int tid = threadIdx.x;
    const int wave = tid >> 6, lane = tid & 63;
    const int quad = lane >> 4, lm = lane & 15;

    __shared__ _Float16 sK[64 * LSTR];
    __shared__ _Float16 sVT[64 * LSTR];
    __shared__ _Float16 sP[4 * 32 * LSTR];
    __shared__ float sInv[192];           // iq | ik | iv
    _Float16* myP = sP + wave * 32 * LSTR;

    if (tid < 192) {
        const int z = tid >> 6, cr = tid & 63;
        const float* cp = colpart + (((size_t)z * 4 + b) * 16) * Cc + h * 64 + cr;
        float s = 0.f;
#pragma unroll
        for (int i = 0; i < 16; ++i) s += cp[(size_t)i * Cc];
        sInv[tid] = rsqrtf(s * (1.0f / Tt) + 1e-4f);
    }
    __syncthreads();

    // Q fragments (B-operand: n=lm=query, k=quad*8+j); iq*ik*scale*log2e folded
    const float QSC = 0.125f * 1.44269504088896f;
    f16x8 qb[2][2];
#pragma unroll
    for (int qf = 0; qf < 2; ++qf) {
        const int row = qt * 128 + wave * 32 + qf * 16 + lm;
#pragma unroll
        for (int ks = 0; ks < 2; ++ks) {
            const int d0 = ks * 32 + quad * 8;
            f16x8 qv = *(const f16x8*)&Qf[(size_t)(b * Tt + row) * Cc + h * 64 + d0];
#pragma unroll
            for (int j = 0; j < 8; ++j)
                qb[qf][ks][j] =
                    (_Float16)((float)qv[j] * sInv[d0 + j] * sInv[64 + d0 + j] * QSC);
        }
    }

    f32x4 o[4][2];      // [cf][qf]: O^T frags (m=channel, n=query)
#pragma unroll
    for (int cf = 0; cf < 4; ++cf)
#pragma unroll
        for (int qf = 0; qf < 2; ++qf) o[cf][qf] = (f32x4){0.f, 0.f, 0.f, 0.f};
    float ls[2] = {0.f, 0.f};

    const int sr0 = tid >> 3, sc0 = (tid & 7) * 8;
    const int sr1 = sr0 + 32;
    const _Float16* gK = Kf + (size_t)b * Tt * Cc + h * 64;
    const _Float16* gV = VT + ((size_t)b * Cc + h * 64) * Tt;

    f16x8 rk0, rk1, rv0, rv1;
    rk0 = *(const f16x8*)&gK[(size_t)sr0 * Cc + sc0];
    rk1 = *(const f16x8*)&gK[(size_t)sr1 * Cc + sc0];
    rv0 = *(const f16x8*)&gV[(size_t)sr0 * Tt + sc0];
    rv1 = *(const f16x8*)&gV[(size_t)sr1 * Tt + sc0];

    for (int kt = 0; kt < 32; ++kt) {
        __syncthreads();
        *(f16x8*)&sK[sr0 * LSTR + sc0]  = rk0;
        *(f16x8*)&sK[sr1 * LSTR + sc0]  = rk1;
        *(f16x8*)&sVT[sr0 * LSTR + sc0] = rv0;
        *(f16x8*)&sVT[sr1 * LSTR + sc0] = rv1;
        __syncthreads();

        if (kt < 31) {
            const int t0 = (kt + 1) * 64;
            rk0 = *(const f16x8*)&gK[(size_t)(t0 + sr0) * Cc + sc0];
            rk1 = *(const f16x8*)&gK[(size_t)(t0 + sr1) * Cc + sc0];
            rv0 = *(const f16x8*)&gV[(size_t)sr0 * Tt + t0 + sc0];
            rv1 = *(const f16x8*)&gV[(size_t)sr1 * Tt + t0 + sc0];
        }

        // ---- S^T = K Q^T
        f32x4 st[4][2];
#pragma unroll
        for (int kf = 0; kf < 4; ++kf)
#pragma unroll
            for (int qf = 0; qf < 2; ++qf) st[kf][qf] = (f32x4){0.f, 0.f, 0.f, 0.f};
#pragma unroll
        for (int ks = 0; ks < 2; ++ks) {
            f16x8 ka[4];
#pragma unroll
            for (int kf = 0; kf < 4; ++kf)
                ka[kf] = *(const f16x8*)&sK[(kf * 16 + lm) * LSTR + ks * 32 + quad * 8];
#pragma unroll
            for (int kf = 0; kf < 4; ++kf)
#pragma unroll
                for (int qf = 0; qf < 2; ++qf)
                    st[kf][qf] = __builtin_amdgcn_mfma_f32_16x16x32_f16(
                        ka[kf], qb[qf][ks], st[kf][qf], 0, 0, 0);
        }

        // ---- p = exp2(s'); P rows packed b64; l partials
#pragma unroll
        for (int kf = 0; kf < 4; ++kf)
#pragma unroll
            for (int qf = 0; qf < 2; ++qf) {
                f16x4 pk;
#pragma unroll
                for (int r = 0; r < 4; ++r) {
                    const float p = exp2f(st[kf][qf][r]);
                    ls[qf] += p;
                    pk[r] = (_Float16)p;
                }
                *(f16x4*)&myP[(qf * 16 + lm) * LSTR + kf * 16 + quad * 4] = pk;
            }

        // ---- O^T += VT P^T (P wave-private)
#pragma unroll
        for (int ks = 0; ks < 2; ++ks) {
            f16x8 pb[2];
#pragma unroll
            for (int qf = 0; qf < 2; ++qf)
                pb[qf] = *(const f16x8*)&myP[(qf * 16 + lm) * LSTR + ks * 32 + quad * 8];
            f16x8 va[4];
#pragma unroll
            for (int cf = 0; cf < 4; ++cf)
                va[cf] = *(const f16x8*)&sVT[(cf * 16 + lm) * LSTR + ks * 32 + quad * 8];
#pragma unroll
            for (int cf = 0; cf < 4; ++cf)
#pragma unroll
                for (int qf = 0; qf < 2; ++qf)
                    o[cf][qf] = __builtin_amdgcn_mfma_f32_16x16x32_f16(
                        va[cf], pb[qf], o[cf][qf], 0, 0, 0);
        }
    }

    // ---- epilogue: l reduce over quads, O /= l, * iv, fp16 out
    float il[2];
#pragma unroll
    for (int qf = 0; qf < 2; ++qf) {
        float s = ls[qf];
        s += __shfl_xor(s, 16, 64);
        s += __shfl_xor(s, 32, 64);
        il[qf] = 1.0f / s;
    }
    float iv[4][4];
#pragma unroll
    for (int cf = 0; cf < 4; ++cf)
#pragma unroll
        for (int r = 0; r < 4; ++r)
            iv[cf][r] = sInv[128 + cf * 16 + quad * 4 + r];
#pragma unroll
    for (int qf = 0; qf < 2; ++qf) {
        const size_t row = (size_t)(b * Tt + qt * 128 + wave * 32 + qf * 16 + lm);
#pragma unroll
        for (int cf = 0; cf < 4; ++cf) {
            f16x4 pk;
#pragma unroll
            for (int r = 0; r < 4; ++r)
                pk[r] = (_Float16)(o[cf][qf][r] * il[qf] * iv[cf][r]);
            *(f16x4*)&AO[row * Cc + h * 64 + cf * 16 + quad * 4] = pk;
        }
    }
}

// ---------------------------------------------------------------------------
// Kernel 3: out = AO @ Wo + bo + residual, fp16 MFMA (R6-validated).
// ---------------------------------------------------------------------------
__global__ __launch_bounds__(256, 2) void out_mfma(
    const _Float16* __restrict__ AO, const _Float16* __restrict__ Wt,
    const float* __restrict__ bo, const float* __restrict__ HS,
    float* __restrict__ Outp)
{
    const int mt = blockIdx.x;              // 128
    const int nt = blockIdx.y;              // 4
    const int tid = threadIdx.x;
    const int wave = tid >> 6, lane = tid & 63;
    const int quad = lane >> 4, lm = lane & 15;
    const int wm = (wave & 1) * 32, wn = (wave >> 1) * 64;

    __shared__ _Float16 sA[64 * 40];
    __shared__ _Float16 sB[128 * 40];

    f32x4 acc[2][4];
#pragma unroll
    for (int mf = 0; mf < 2; ++mf)
#pragma unroll
        for (int nf = 0; nf < 4; ++nf) acc[mf][nf] = (f32x4){0.f, 0.f, 0.f, 0.f};

    const int ra = tid >> 2, ka = (tid & 3) * 8;
    const int rb = tid >> 1, kb = (tid & 1) * 16;
    const _Float16* gah = AO + (size_t)(mt * 64 + ra) * Cc + ka;
    const _Float16* gbh = Wt + ((size_t)(3 * 512 + nt * 128 + rb)) * Cc + kb;

    for (int k0 = 0; k0 < Cc; k0 += 32) {
        __syncthreads();
        {
            *(f16x8*)&sA[ra * 40 + ka]     = *(const f16x8*)&gah[k0];
            *(f16x8*)&sB[rb * 40 + kb]     = *(const f16x8*)&gbh[k0];
            *(f16x8*)&sB[rb * 40 + kb + 8] = *(const f16x8*)&gbh[k0 + 8];
        }
        __syncthreads();

        f16x8 ah[2], bh[4];
#pragma unroll
        for (int mf = 0; mf < 2; ++mf)
            ah[mf] = *(const f16x8*)&sA[(wm + mf * 16 + lm) * 40 + quad * 8];
#pragma unroll
        for (int nf = 0; nf < 4; ++nf)
            bh[nf] = *(const f16x8*)&sB[(wn + nf * 16 + lm) * 40 + quad * 8];
#pragma unroll
        for (int mf = 0; mf < 2; ++mf)
#pragma unroll
            for (int nf = 0; nf < 4; ++nf)
                acc[mf][nf] = __builtin_amdgcn_mfma_f32_16x16x32_f16(ah[mf], bh[nf], acc[mf][nf], 0, 0, 0);
    }

#pragma unroll
    for (int mf = 0; mf < 2; ++mf)
#pragma unroll
        for (int r = 0; r < 4; ++r) {
            const size_t m = (size_t)(mt * 64 + wm + mf * 16 + quad * 4 + r);
#pragma unroll
            for (int nf = 0; nf < 4; ++nf) {
                const int col = nt * 128 + wn + nf * 16 + lm;
                Outp[m * Cc + col] = acc[mf][nf][r] + bo[col] + HS[m * Cc + col];
            }
        }
}

// ---------------------------------------------------------------------------
extern "C" void kernel_launch(void* const* d_in, const int* in_sizes, int n_in,
                              void* d_out, int out_size, void* d_ws,
                              size_t ws_size, hipStream_t stream)
{
    const float* HS = (const float*)d_in[0];
    const float* Wq = (const float*)d_in[1];
    const float* Wk = (const float*)d_in[2];
    const float* Wv = (const float*)d_in[3];
    const float* Wo = (const float*)d_in[4];
    const float* bo = (const float*)d_in[5];
    float* out = (float*)d_out;

    const size_t SZ = (size_t)Bb * Tt * Cc;        // 4,194,304 elements
    _Float16* Qf  = (_Float16*)d_ws;
    _Float16* Kf  = Qf + SZ;
    _Float16* VTh = Kf + SZ;
    _Float16* AO  = VTh + SZ;
    _Float16* Wt  = AO + SZ;                        // 4*Cc*Cc halves
    float* colpart = (float*)(Wt + 4 * Cc * Cc);    // 3*4*16*512 floats

    wsetup<<<dim3(64, 4), 256, 0, stream>>>(Wq, Wk, Wv, Wo, Wt);

    qkv_mfma<<<dim3(64, 4, 3), 256, 0, stream>>>(HS, Wt, Qf, Kf, VTh, colpart);

    attn_mfma<<<512, 256, 0, stream>>>(Qf, Kf, VTh, colpart, AO);

    out_mfma<<<dim3(128, 4), 256, 0, stream>>>(AO, Wt, bo, HS, out);
}